// Round 1
// baseline (363.581 us; speedup 1.0000x reference)
//
#include <hip/hip_runtime.h>

// Problem constants (match reference setup_inputs / module constants)
#define BB 16
#define LL 4096
#define GG 256
#define RR 84
#define WW 169      // 2*R+1
#define DD 12
#define VOCAB 25    // 2*D+1

// Output element offsets (int32 elements, concat in return order)
#define S_L2L (BB * LL * WW)   // 11,075,584
#define S_G2G (BB * GG * GG)   //  1,048,576
#define S_L2G (BB * LL * GG)   // 16,777,216
#define S_G2L (BB * GG * LL)   // 16,777,216
#define OFF0 0
#define OFF1 (OFF0 + S_L2L)
#define OFF2 (OFF1 + S_G2G)
#define OFF3 (OFF2 + S_L2G)
#define OFF4 (OFF3 + S_G2L)
#define OFF5 (OFF4 + S_L2L)
#define OFF6 (OFF5 + S_G2G)
#define OFF7 (OFF6 + S_L2G)

// -------- suffix-cumsum kernel: one block (256 threads) per batch --------
__global__ void scan_kernel(const int* __restrict__ long_bp,
                            const int* __restrict__ glob_bp,
                            int* __restrict__ long_seg,
                            int* __restrict__ glob_seg) {
    const int b = blockIdx.x;
    const int t = threadIdx.x;  // 256 threads
    __shared__ int part[256];

    // ---- long: 4096 elems, 16 per thread ----
    const int* bp = long_bp + b * LL;
    int vals[16];
    int s = 0;
#pragma unroll
    for (int j = 0; j < 16; ++j) { vals[j] = bp[t * 16 + j]; s += vals[j]; }
    part[t] = s;
    __syncthreads();
    for (int off = 1; off < 256; off <<= 1) {
        int v = (t >= off) ? part[t - off] : 0;
        __syncthreads();
        part[t] += v;
        __syncthreads();
    }
    const int total = part[255];
    int run = (t == 0) ? 0 : part[t - 1];   // exclusive prefix at chunk start
    int* seg = long_seg + b * LL;
#pragma unroll
    for (int j = 0; j < 16; ++j) {
        seg[t * 16 + j] = total - run;      // suffix sum incl. element
        run += vals[j];
    }
    __syncthreads();

    // ---- glob: 256 elems, 1 per thread ----
    const int gv = glob_bp[b * GG + t];
    part[t] = gv;
    __syncthreads();
    for (int off = 1; off < 256; off <<= 1) {
        int v = (t >= off) ? part[t - off] : 0;
        __syncthreads();
        part[t] += v;
        __syncthreads();
    }
    const int gtot = part[255];
    const int gexcl = (t == 0) ? 0 : part[t - 1];
    glob_seg[b * GG + t] = gtot - gexcl;
}

// -------- l2l: mask + rel, thread per element --------
__global__ void l2l_kernel(const int* __restrict__ long_seg,
                           int* __restrict__ out_mask,
                           int* __restrict__ out_rel) {
    const unsigned idx = blockIdx.x * blockDim.x + threadIdx.x;  // exact grid
    const unsigned k = idx % WW;
    const unsigned row = idx / WW;          // b*L + i
    const int i = (int)(row & (LL - 1));
    const int segi = long_seg[row];
    const int j = i + (int)k - RR;
    int mask = 0;
    if (j >= 0 && j < LL) {
        mask = (long_seg[(int)row - i + j] == segi) ? 1 : 0;
    }
    int c = (int)k - RR;
    c = c < -DD ? -DD : (c > DD ? DD : c);
    const int rel = (c >= 0) ? c : (DD - c);
    out_mask[idx] = mask;
    out_rel[idx]  = rel;
}

// -------- g2g: mask + rel, thread per element --------
__global__ void g2g_kernel(const int* __restrict__ glob_seg,
                           int* __restrict__ out_mask,
                           int* __restrict__ out_rel) {
    const int idx = blockIdx.x * blockDim.x + threadIdx.x;
    const int h = idx & (GG - 1);
    const int g = (idx >> 8) & (GG - 1);
    const int b = idx >> 16;
    const int segg = glob_seg[b * GG + g];
    const int segh = glob_seg[b * GG + h];
    const int tokg = segg > 0 ? 1 : 0;
    const int tokh = segh > 0 ? 1 : 0;
    int c = h - g;
    c = c < -DD ? -DD : (c > DD ? DD : c);
    const int r0 = (c >= 0) ? c : (DD - c);
    out_mask[idx] = (tokg == tokh) ? 1 : 0;
    out_rel[idx]  = (segg == segh) ? r0 : (VOCAB + 2);
}

// -------- l2g: mask + rel, int4 over g --------
__global__ void l2g_kernel(const int* __restrict__ long_seg,
                           const int* __restrict__ long_pid,
                           const int* __restrict__ glob_seg,
                           int* __restrict__ out_mask,
                           int* __restrict__ out_rel) {
    const int t = blockIdx.x * blockDim.x + threadIdx.x;  // B*L*G/4 threads
    const int g0 = (t & 63) * 4;        // 64 int4 groups per row of G=256
    const int row = t >> 6;             // b*L + i
    const int b = row >> 12;
    const int tokl = long_seg[row] > 0 ? 1 : 0;
    const int pid = long_pid[row];
    const int4 sg = *(const int4*)(glob_seg + b * GG + g0);
    int4 m, r;
    {
        const int tokg = sg.x > 0 ? 1 : 0; const int eq = (pid == (g0 + 0));
        m.x = (tokl == tokg) ? eq : 0;     r.x = eq + VOCAB;
    }
    {
        const int tokg = sg.y > 0 ? 1 : 0; const int eq = (pid == (g0 + 1));
        m.y = (tokl == tokg) ? eq : 0;     r.y = eq + VOCAB;
    }
    {
        const int tokg = sg.z > 0 ? 1 : 0; const int eq = (pid == (g0 + 2));
        m.z = (tokl == tokg) ? eq : 0;     r.z = eq + VOCAB;
    }
    {
        const int tokg = sg.w > 0 ? 1 : 0; const int eq = (pid == (g0 + 3));
        m.w = (tokl == tokg) ? eq : 0;     r.w = eq + VOCAB;
    }
    *(int4*)(out_mask + 4 * (size_t)t) = m;
    *(int4*)(out_rel  + 4 * (size_t)t) = r;
}

// -------- g2l: mask + rel, int4 over i --------
__global__ void g2l_kernel(const int* __restrict__ long_seg,
                           const int* __restrict__ long_pid,
                           const int* __restrict__ glob_seg,
                           int* __restrict__ out_mask,
                           int* __restrict__ out_rel) {
    const int t = blockIdx.x * blockDim.x + threadIdx.x;  // B*G*L/4 threads
    const int i0 = (t & 1023) * 4;      // 1024 int4 groups per row of L=4096
    const int row = t >> 10;            // b*G + g
    const int g = row & (GG - 1);
    const int b = row >> 8;
    const int tokg = glob_seg[row] > 0 ? 1 : 0;
    const int4 pid4 = *(const int4*)(long_pid + b * LL + i0);
    const int4 seg4 = *(const int4*)(long_seg + b * LL + i0);
    int4 m, r;
    {
        const int tokl = seg4.x > 0 ? 1 : 0; const int eq = (g == pid4.x);
        const int allow = eq | (g == 0);
        m.x = (tokl == tokg) ? allow : 0;    r.x = eq + VOCAB;
    }
    {
        const int tokl = seg4.y > 0 ? 1 : 0; const int eq = (g == pid4.y);
        const int allow = eq | (g == 0);
        m.y = (tokl == tokg) ? allow : 0;    r.y = eq + VOCAB;
    }
    {
        const int tokl = seg4.z > 0 ? 1 : 0; const int eq = (g == pid4.z);
        const int allow = eq | (g == 0);
        m.z = (tokl == tokg) ? allow : 0;    r.z = eq + VOCAB;
    }
    {
        const int tokl = seg4.w > 0 ? 1 : 0; const int eq = (g == pid4.w);
        const int allow = eq | (g == 0);
        m.w = (tokl == tokg) ? allow : 0;    r.w = eq + VOCAB;
    }
    *(int4*)(out_mask + 4 * (size_t)t) = m;
    *(int4*)(out_rel  + 4 * (size_t)t) = r;
}

extern "C" void kernel_launch(void* const* d_in, const int* in_sizes, int n_in,
                              void* d_out, int out_size, void* d_ws, size_t ws_size,
                              hipStream_t stream) {
    const int* long_bp  = (const int*)d_in[0];  // (B, L)
    const int* long_pid = (const int*)d_in[1];  // (B, L)
    const int* glob_bp  = (const int*)d_in[2];  // (B, G)
    int* out = (int*)d_out;

    // workspace: long_seg (B*L) then glob_seg (B*G) — 278,528 bytes
    int* long_seg = (int*)d_ws;
    int* glob_seg = long_seg + BB * LL;

    scan_kernel<<<BB, 256, 0, stream>>>(long_bp, glob_bp, long_seg, glob_seg);

    l2l_kernel<<<S_L2L / 256, 256, 0, stream>>>(long_seg, out + OFF0, out + OFF4);
    g2g_kernel<<<S_G2G / 256, 256, 0, stream>>>(glob_seg, out + OFF1, out + OFF5);
    l2g_kernel<<<(S_L2G / 4) / 256, 256, 0, stream>>>(long_seg, long_pid, glob_seg,
                                                      out + OFF2, out + OFF6);
    g2l_kernel<<<(S_G2L / 4) / 256, 256, 0, stream>>>(long_seg, long_pid, glob_seg,
                                                      out + OFF3, out + OFF7);
}

// Round 2
// 358.513 us; speedup vs baseline: 1.0141x; 1.0141x over previous
//
#include <hip/hip_runtime.h>

// Problem constants (match reference setup_inputs / module constants)
#define BB 16
#define LL 4096
#define GG 256
#define RR 84
#define WW 169      // 2*R+1
#define DD 12
#define VOCAB 25    // 2*D+1

// Output element offsets (int32 elements, concat in return order)
#define S_L2L (BB * LL * WW)   // 11,075,584
#define S_G2G (BB * GG * GG)   //  1,048,576
#define S_L2G (BB * LL * GG)   // 16,777,216
#define S_G2L (BB * GG * LL)   // 16,777,216
#define OFF0 0
#define OFF1 (OFF0 + S_L2L)
#define OFF2 (OFF1 + S_G2G)
#define OFF3 (OFF2 + S_L2G)
#define OFF4 (OFF3 + S_G2L)
#define OFF5 (OFF4 + S_L2L)
#define OFF6 (OFF5 + S_G2G)
#define OFF7 (OFF6 + S_L2G)

// Fused writer: 1024 output elements (per stream) per 256-thread block,
// 4 consecutive elements (one int4) per thread per stream.
#define NB_L2L (S_L2L / 1024)   // 10816
#define NB_G2G (S_G2G / 1024)   //  1024
#define NB_L2G (S_L2G / 1024)   // 16384
#define NB_G2L (S_G2L / 1024)   // 16384
#define NB_TOTAL (NB_L2L + NB_G2G + NB_L2G + NB_G2L)  // 44608

// -------- suffix-cumsum kernel: one block (256 threads) per batch --------
__global__ void scan_kernel(const int* __restrict__ long_bp,
                            const int* __restrict__ glob_bp,
                            int* __restrict__ long_seg,
                            int* __restrict__ glob_seg) {
    const int b = blockIdx.x;
    const int t = threadIdx.x;  // 256 threads
    __shared__ int part[256];

    // ---- long: 4096 elems, 16 per thread ----
    const int* bp = long_bp + b * LL;
    int vals[16];
    int s = 0;
#pragma unroll
    for (int j = 0; j < 16; ++j) { vals[j] = bp[t * 16 + j]; s += vals[j]; }
    part[t] = s;
    __syncthreads();
    for (int off = 1; off < 256; off <<= 1) {
        int v = (t >= off) ? part[t - off] : 0;
        __syncthreads();
        part[t] += v;
        __syncthreads();
    }
    const int total = part[255];
    int run = (t == 0) ? 0 : part[t - 1];   // exclusive prefix at chunk start
    int* seg = long_seg + b * LL;
#pragma unroll
    for (int j = 0; j < 16; ++j) {
        seg[t * 16 + j] = total - run;      // suffix sum incl. element
        run += vals[j];
    }
    __syncthreads();

    // ---- glob: 256 elems, 1 per thread ----
    const int gv = glob_bp[b * GG + t];
    part[t] = gv;
    __syncthreads();
    for (int off = 1; off < 256; off <<= 1) {
        int v = (t >= off) ? part[t - off] : 0;
        __syncthreads();
        part[t] += v;
        __syncthreads();
    }
    const int gtot = part[255];
    const int gexcl = (t == 0) ? 0 : part[t - 1];
    glob_seg[b * GG + t] = gtot - gexcl;
}

// -------- fused writer: all 4 (mask, rel) pairs, int4 stores everywhere ----
__global__ __launch_bounds__(256) void fused_writer(
        const int* __restrict__ long_seg,
        const int* __restrict__ long_pid,
        const int* __restrict__ glob_seg,
        int* __restrict__ out) {
    const int blk = blockIdx.x;
    const int tid = threadIdx.x;

    if (blk < NB_L2L) {
        // ---- l2l: flat over (b*L + i) * 169 + k ----
        unsigned f = (unsigned)blk * 1024u + (unsigned)tid * 4u;
        unsigned row = f / (unsigned)WW;          // b*L + i
        int k = (int)(f - row * (unsigned)WW);
        int i = (int)(row & (LL - 1));
        unsigned base = row - (unsigned)i;        // b*L
        int segi = long_seg[row];
        int m[4], r[4];
#pragma unroll
        for (int e = 0; e < 4; ++e) {
            const int j = i + k - RR;
            int msk = 0;
            if (j >= 0 && j < LL) msk = (long_seg[base + (unsigned)j] == segi) ? 1 : 0;
            int c = k - RR;
            c = c < -DD ? -DD : (c > DD ? DD : c);
            r[e] = (c >= 0) ? c : (DD - c);
            m[e] = msk;
            if (e < 3) {
                if (++k == WW) {
                    k = 0; ++row;
                    i = (int)(row & (LL - 1));
                    base = row - (unsigned)i;
                    segi = long_seg[row];
                }
            }
        }
        *(int4*)(out + OFF0 + f) = make_int4(m[0], m[1], m[2], m[3]);
        *(int4*)(out + OFF4 + f) = make_int4(r[0], r[1], r[2], r[3]);

    } else if (blk < NB_L2L + NB_G2G) {
        // ---- g2g: flat over (b*G + g) * G + h ----
        const int blk2 = blk - NB_L2L;
        const unsigned f = (unsigned)blk2 * 1024u + (unsigned)tid * 4u;
        const int h0 = (int)(f & (GG - 1));       // multiple of 4
        const unsigned row = f >> 8;              // b*G + g
        const int g = (int)(row & (GG - 1));
        const int segg = glob_seg[row];
        const int tokg = segg > 0 ? 1 : 0;
        const int4 sh = *(const int4*)(glob_seg + (row - (unsigned)g) + (unsigned)h0);
        const int sgh[4] = {sh.x, sh.y, sh.z, sh.w};
        int m[4], r[4];
#pragma unroll
        for (int e = 0; e < 4; ++e) {
            const int tokh = sgh[e] > 0 ? 1 : 0;
            int c = (h0 + e) - g;
            c = c < -DD ? -DD : (c > DD ? DD : c);
            const int r0 = (c >= 0) ? c : (DD - c);
            m[e] = (tokg == tokh) ? 1 : 0;
            r[e] = (segg == sgh[e]) ? r0 : (VOCAB + 2);
        }
        *(int4*)(out + OFF1 + f) = make_int4(m[0], m[1], m[2], m[3]);
        *(int4*)(out + OFF5 + f) = make_int4(r[0], r[1], r[2], r[3]);

    } else if (blk < NB_L2L + NB_G2G + NB_L2G) {
        // ---- l2g: flat over (b*L + i) * G + g ----
        const int blk3 = blk - (NB_L2L + NB_G2G);
        const unsigned f = (unsigned)blk3 * 1024u + (unsigned)tid * 4u;
        const int g0 = (int)(f & (GG - 1));       // multiple of 4
        const unsigned row = f >> 8;              // b*L + i
        const int b = (int)(row >> 12);
        const int tokl = long_seg[row] > 0 ? 1 : 0;
        const int pid = long_pid[row];
        const int4 sg = *(const int4*)(glob_seg + b * GG + g0);
        const int sgv[4] = {sg.x, sg.y, sg.z, sg.w};
        int m[4], r[4];
#pragma unroll
        for (int e = 0; e < 4; ++e) {
            const int tokg = sgv[e] > 0 ? 1 : 0;
            const int eq = (pid == (g0 + e)) ? 1 : 0;
            m[e] = (tokl == tokg) ? eq : 0;
            r[e] = eq + VOCAB;
        }
        *(int4*)(out + OFF2 + f) = make_int4(m[0], m[1], m[2], m[3]);
        *(int4*)(out + OFF6 + f) = make_int4(r[0], r[1], r[2], r[3]);

    } else {
        // ---- g2l: flat over (b*G + g) * L + i ----
        const int blk4 = blk - (NB_L2L + NB_G2G + NB_L2G);
        const unsigned f = (unsigned)blk4 * 1024u + (unsigned)tid * 4u;
        const int i0 = (int)(f & (LL - 1));       // multiple of 4
        const unsigned row = f >> 12;             // b*G + g
        const int g = (int)(row & (GG - 1));
        const int b = (int)(row >> 8);
        const int tokg = glob_seg[row] > 0 ? 1 : 0;
        const int4 pid4 = *(const int4*)(long_pid + b * LL + i0);
        const int4 seg4 = *(const int4*)(long_seg + b * LL + i0);
        const int pidv[4] = {pid4.x, pid4.y, pid4.z, pid4.w};
        const int segv[4] = {seg4.x, seg4.y, seg4.z, seg4.w};
        const int gz = (g == 0) ? 1 : 0;
        int m[4], r[4];
#pragma unroll
        for (int e = 0; e < 4; ++e) {
            const int tokl = segv[e] > 0 ? 1 : 0;
            const int eq = (g == pidv[e]) ? 1 : 0;
            const int allow = eq | gz;
            m[e] = (tokl == tokg) ? allow : 0;
            r[e] = eq + VOCAB;
        }
        *(int4*)(out + OFF3 + f) = make_int4(m[0], m[1], m[2], m[3]);
        *(int4*)(out + OFF7 + f) = make_int4(r[0], r[1], r[2], r[3]);
    }
}

extern "C" void kernel_launch(void* const* d_in, const int* in_sizes, int n_in,
                              void* d_out, int out_size, void* d_ws, size_t ws_size,
                              hipStream_t stream) {
    const int* long_bp  = (const int*)d_in[0];  // (B, L)
    const int* long_pid = (const int*)d_in[1];  // (B, L)
    const int* glob_bp  = (const int*)d_in[2];  // (B, G)
    int* out = (int*)d_out;

    // workspace: long_seg (B*L) then glob_seg (B*G) — 278,528 bytes
    int* long_seg = (int*)d_ws;
    int* glob_seg = long_seg + BB * LL;

    scan_kernel<<<BB, 256, 0, stream>>>(long_bp, glob_bp, long_seg, glob_seg);
    fused_writer<<<NB_TOTAL, 256, 0, stream>>>(long_seg, long_pid, glob_seg, out);
}